// Round 3
// baseline (107.479 us; speedup 1.0000x reference)
//
#include <hip/hip_runtime.h>

// ---------------- problem constants ----------------
#define NBLK   98304     // 8*3*64*64 total 8x8 blocks
#define NPB    12288     // blocks per batch (3*64*64)
#define HW     512
#define NUMBITS 4096
#define RANK0  29490ULL  // floor(0.3*(NBLK-1))
#define RANK1  29491ULL
#define STEGO_N 6291456  // 8*3*512*512
#define ELIG   111       // ceil(4096/37) blocks contain eligible coefficients

// ---------------- DCT matrix as compile-time constants ----------------
struct DTab { double d[8][8]; };

constexpr double CT_[9] = {
  1.0,
  0.98078528040323044913,
  0.92387953251128675613,
  0.83146961230254523708,
  0.70710678118654752440,
  0.55557023301960222474,
  0.38268343236508977173,
  0.19509032201612826785,
  0.0
};
constexpr double cospi16(int m){           // cos(pi*m/16), m >= 0
  int r = m % 32;
  return (r<=8) ? CT_[r] : (r<=16) ? -CT_[16-r] : (r<=24) ? -CT_[r-16] : CT_[32-r];
}
constexpr DTab make_dtab(){
  DTab t{};
  for(int k=0;k<8;k++) for(int n=0;n<8;n++){
    double s = (k==0) ? 0.35355339059327376220 : 0.5; // sqrt(1/8), sqrt(2/8)
    t.d[k][n] = s * cospi16((2*n+1)*k);
  }
  return t;
}
constexpr DTab DT = make_dtab();

constexpr unsigned long long make_fmask(){ // bit u*8+v set iff 3 <= u+v <= 8
  unsigned long long m = 0;
  for(int u=0;u<8;u++) for(int v=0;v<8;v++){
    int s=u+v; if(s>=3 && s<=8) m |= (1ULL << (u*8+v));
  }
  return m;
}
constexpr unsigned long long FMASK = make_fmask();  // 37 bits set

// ---------------- kernels ----------------

// fused: stego = cover (copy), map = 0, per-block fp64 variance,
// plus zero-init of bins / done-counters / publish flags (replaces memset dispatch)
__global__ __launch_bounds__(256) void k_stats(const float* __restrict__ cover,
    float* __restrict__ out, double* __restrict__ var,
    unsigned* __restrict__ bins, unsigned* __restrict__ cnt,
    unsigned* __restrict__ pub){
  int i = blockIdx.x*256 + threadIdx.x;     // block id over (b,c,n,m)
  if(i < 6*4096) bins[i] = 0u;
  if(i < 6)      cnt[i]  = 0u;
  if(i < 96)     pub[i]  = 0u;
  int m = i & 63, n = (i>>6)&63, bc = i>>12;
  const float* p  = cover + ((size_t)bc*HW + (size_t)n*8)*HW + (size_t)m*8;
  float*       po = out   + ((size_t)bc*HW + (size_t)n*8)*HW + (size_t)m*8;
  double s1=0.0, s2=0.0;
#pragma unroll
  for(int r=0;r<8;r++){
    const float4* q = (const float4*)(p + (size_t)r*HW);
    float4 a = q[0], b = q[1];
    float4* w = (float4*)(po + (size_t)r*HW);
    w[0]=a; w[1]=b;
    double x;
    x=(double)a.x; s1+=x; s2+=x*x;
    x=(double)a.y; s1+=x; s2+=x*x;
    x=(double)a.z; s1+=x; s2+=x*x;
    x=(double)a.w; s1+=x; s2+=x*x;
    x=(double)b.x; s1+=x; s2+=x*x;
    x=(double)b.y; s1+=x; s2+=x*x;
    x=(double)b.z; s1+=x; s2+=x*x;
    x=(double)b.w; s1+=x; s2+=x*x;
  }
  double mean = s1*(1.0/64.0);
  double v = s2*(1.0/64.0) - mean*mean;
  if(v < 0.0) v = 0.0;
  var[i] = v;
  // zero the embedding map for this block (fixed up later for eligible blocks)
  float4 z = make_float4(0.f,0.f,0.f,0.f);
  float4* pm = (float4*)(out + (size_t)STEGO_N + (size_t)i*64);
#pragma unroll
  for(int j=0;j<16;j++) pm[j] = z;
}

// fused radix-select round: LDS histogram -> global merge -> last WG picks digit.
__global__ __launch_bounds__(1024) void k_round(const double* __restrict__ var,
    unsigned* __restrict__ bins, unsigned* __restrict__ cnt,
    unsigned long long* __restrict__ pref, unsigned long long* __restrict__ rank,
    int r, int shift, int highshift, int nbins, int last,
    double* __restrict__ scal){
  __shared__ unsigned h[4096];
  __shared__ unsigned sb[1024];
  __shared__ int lastflag;
  int tid = threadIdx.x;
  for(int j=tid;j<4096;j+=1024) h[j]=0;
  __syncthreads();
  int i = blockIdx.x*1024 + tid;
  unsigned long long bits = (unsigned long long)__double_as_longlong(var[i]);
  unsigned bin = (unsigned)((bits>>shift) & (unsigned long long)(nbins-1));
#pragma unroll
  for(int s=0;s<2;s++){
    bool match;
    if(r==0) match = true;
    else { unsigned long long pf = pref[s]; match = ((bits>>highshift)==(pf>>highshift)); }
    if(match) atomicAdd(&h[s*2048+bin], 1u);
  }
  __syncthreads();
  unsigned* gb = bins + r*4096;
  for(int j=tid;j<4096;j+=1024){
    unsigned v=h[j];
    if(v) atomicAdd(&gb[j], v);
  }
  __syncthreads();
  if(tid==0){
    __threadfence();
    unsigned old = __hip_atomic_fetch_add(&cnt[r], 1u, __ATOMIC_ACQ_REL, __HIP_MEMORY_SCOPE_AGENT);
    lastflag = (old == 95u) ? 1 : 0;
  }
  __syncthreads();
  if(!lastflag) return;

  // ---- pick phase (only the last-arriving WG runs this) ----
  for(int s=0;s<2;s++){
    unsigned long long rk = (r==0) ? (s ? RANK1 : RANK0) : rank[s];
    unsigned* bb = gb + s*2048;
    unsigned a0 = (2*tid   < nbins) ? __hip_atomic_load(&bb[2*tid],   __ATOMIC_RELAXED, __HIP_MEMORY_SCOPE_AGENT) : 0u;
    unsigned a1 = (2*tid+1 < nbins) ? __hip_atomic_load(&bb[2*tid+1], __ATOMIC_RELAXED, __HIP_MEMORY_SCOPE_AGENT) : 0u;
    unsigned part = a0+a1;
    sb[tid]=part; __syncthreads();
    for(int off=1;off<1024;off<<=1){
      unsigned add = (tid>=off)? sb[tid-off] : 0u;
      __syncthreads();
      sb[tid]+=add;
      __syncthreads();
    }
    unsigned incl=sb[tid], excl=incl-part;
    if(rk >= (unsigned long long)excl && rk < (unsigned long long)incl){
      int j; unsigned base;
      if(rk < (unsigned long long)excl + a0){ j=2*tid;   base=excl; }
      else                                  { j=2*tid+1; base=excl+a0; }
      unsigned long long p = (r==0) ? 0ULL : pref[s];
      pref[s] = p | ((unsigned long long)j << shift);
      rank[s] = rk - base;
    }
    __syncthreads();
  }
  if(last && tid==0){
    double A  = __longlong_as_double((long long)pref[0]); // s[29490]
    double Bv = __longlong_as_double((long long)pref[1]); // s[29491]
    // selection (var_norm > thr) is monotone-equivalent to var > A + 0.9*(B-A)
    scal[0] = A + 0.9*(Bv - A);
  }
}

// fused: texture mask + WG scan + decoupled-lookback global prefix + wave-shuffle embed
__global__ __launch_bounds__(1024) void k_texembed(const float* __restrict__ cover,
    const int* __restrict__ secret, const double* __restrict__ var,
    const double* __restrict__ scal, unsigned* __restrict__ pub,
    float* __restrict__ out){
  __shared__ int sb[1024];
  __shared__ int qi[128], qs[128];
  __shared__ int qcnt;
  int tid = threadIdx.x;
  int g = blockIdx.x;
  int i = g*1024 + tid;
  if(tid==0) qcnt = 0;
  double thr = scal[0];
  int f = (var[i] > thr) ? 1 : 0;
  sb[tid]=f; __syncthreads();
  for(int off=1;off<1024;off<<=1){
    int add = (tid>=off)? sb[tid-off] : 0;
    __syncthreads();
    sb[tid]+=add;
    __syncthreads();
  }
  int incl = sb[tid];
  int P = incl - f;
  if(tid==1023){
    __hip_atomic_store(&pub[g], (unsigned)incl + 1u, __ATOMIC_RELEASE, __HIP_MEMORY_SCOPE_AGENT);
  }
  // decoupled lookback: threads 0..g-1 spin in parallel on predecessors' sums
  int ov = 0;
  if(tid < g){
    unsigned v;
    do { v = __hip_atomic_load(&pub[tid], __ATOMIC_ACQUIRE, __HIP_MEMORY_SCOPE_AGENT); } while(v==0u);
    ov = (int)(v - 1u);
  }
  __syncthreads();           // sb free for reuse
  sb[tid]=ov; __syncthreads();
  for(int off=512; off>0; off>>=1){
    if(tid<off) sb[tid] += sb[tid+off];
    __syncthreads();
  }
  int O = sb[0];
  int S = O + P;             // # selected blocks strictly before block i
  if(f && S < ELIG){
    int q = atomicAdd(&qcnt, 1);
    qi[q] = i; qs[q] = S;
  }
  __syncthreads();
  int nq = qcnt;
  if(nq == 0) return;

  // wave-parallel embed: lane l owns coefficient/pixel (l>>3, l&7); fp64 via shuffles
  int wid = tid >> 6, lane = tid & 63;
  int lr = lane >> 3, lc = lane & 7;
  for(int q = wid; q < nq; q += 16){
    int bi = qi[q], S2 = qs[q];
    int m = bi & 63, n = (bi>>6)&63, bc = bi>>12, b = bi / NPB;
    const float* p  = cover + ((size_t)bc*HW + (size_t)n*8)*HW + (size_t)m*8;
    float*       po = out   + ((size_t)bc*HW + (size_t)n*8)*HW + (size_t)m*8;
    double x = (double)p[(size_t)lr*HW + lc];     // X[lr][lc]
    // stage1: T1[r][v] = sum_j X[r][j]*D[v][j]
    double t1 = 0.0;
#pragma unroll
    for(int j=0;j<8;j++) t1 += __shfl(x, lr*8+j) * DT.d[lc][j];
    // stage2: C[u][v] = sum_k D[u][k]*T1[k][v]
    double coef = 0.0;
#pragma unroll
    for(int k=0;k<8;k++) coef += DT.d[lr][k] * __shfl(t1, k*8+lc);
    // embedding
    bool sel = (FMASK>>lane)&1ULL;
    float mv = 0.f;
    if(sel){
      int fp  = (int)__popcll(FMASK & ((1ULL<<lane)-1ULL));
      int ord = 37*S2 + fp;
      if(ord < NUMBITS){
        mv = 1.f;
        double rnd = rint(coef);                  // round half-to-even == jnp.round
        int lsb = ((int)fabs(rnd)) & 1;
        int bit = secret[(size_t)b*NUMBITS + ord];
        if(lsb != bit) coef += ((coef>=0.0)?1.0:-1.0)*(2.0*(double)bit-1.0)*0.5;
      }
    }
    out[(size_t)STEGO_N + (size_t)bi*64 + lane] = mv;
    // inv stage1: T2[r][v] = sum_u D[u][r]*M[u][v]
    double t2 = 0.0;
#pragma unroll
    for(int u=0;u<8;u++) t2 += DT.d[u][lr] * __shfl(coef, u*8+lc);
    // inv stage2: pix[r][k] = sum_q T2[r][q]*D[q][k]
    double px = 0.0;
#pragma unroll
    for(int qq=0;qq<8;qq++) px += __shfl(t2, lr*8+qq) * DT.d[qq][lc];
    po[(size_t)lr*HW + lc] = (float)px;
  }
}

// ---------------- host launch ----------------
extern "C" void kernel_launch(void* const* d_in, const int* in_sizes, int n_in,
                              void* d_out, int out_size, void* d_ws, size_t ws_size,
                              hipStream_t stream) {
  const float* cover  = (const float*)d_in[0];
  const int*   secret = (const int*)d_in[1];
  float* out = (float*)d_out;
  char*  ws  = (char*)d_ws;

  // ws layout (bytes)
  double* var  = (double*)(ws);                     // 98304*8   = 786432
  unsigned* bins = (unsigned*)(ws + 786432);        // 6*4096*4  = 98304  -> 884736
  unsigned* cnt  = (unsigned*)(ws + 884736);        // 6*4       -> 884760
  unsigned* pub  = (unsigned*)(ws + 884760);        // 96*4      -> 885144
  unsigned long long* pref = (unsigned long long*)(ws + 885152); // [2]
  unsigned long long* rank = (unsigned long long*)(ws + 885168); // [2]
  double* scal = (double*)(ws + 885184);            // raw threshold

  // fused copy + map-zero + variance + scratch-zero
  k_stats<<<NBLK/256, 256, 0, stream>>>(cover, out, var, bins, cnt, pub);

  const int shifts[6] = {53,42,31,20,9,0};
  const int nb[6]     = {2048,2048,2048,2048,2048,512};
  for(int r=0;r<6;r++){
    int highshift = (r==0) ? 64 : shifts[r-1];
    k_round<<<NBLK/1024, 1024, 0, stream>>>(var, bins, cnt, pref, rank,
                                            r, shifts[r], highshift, nb[r],
                                            (r==5)?1:0, scal);
  }

  k_texembed<<<NBLK/1024, 1024, 0, stream>>>(cover, secret, var, scal, pub, out);
}

// Round 4
// 66.176 us; speedup vs baseline: 1.6241x; 1.6241x over previous
//
#include <hip/hip_runtime.h>

// ---------------- problem constants ----------------
#define NBLK   98304     // 8*3*64*64 total 8x8 blocks
#define NPB    12288     // blocks per batch (3*64*64)
#define HW     512
#define NUMBITS 4096
#define RANK0  29490     // floor(0.3*(NBLK-1))
#define RANK1  29491
#define STEGO_N 6291456  // 8*3*512*512
#define ELIG   111       // ceil(4096/37) blocks contain eligible coefficients
#define HIST   16384
#define CANDCAP 8192
#define NWG384 384       // k_stats workgroups

typedef unsigned long long ull;

// ---------------- DCT matrix as compile-time constants ----------------
struct DTab { double d[8][8]; };

constexpr double CT_[9] = {
  1.0,
  0.98078528040323044913,
  0.92387953251128675613,
  0.83146961230254523708,
  0.70710678118654752440,
  0.55557023301960222474,
  0.38268343236508977173,
  0.19509032201612826785,
  0.0
};
constexpr double cospi16(int m){           // cos(pi*m/16), m >= 0
  int r = m % 32;
  return (r<=8) ? CT_[r] : (r<=16) ? -CT_[16-r] : (r<=24) ? -CT_[r-16] : CT_[32-r];
}
constexpr DTab make_dtab(){
  DTab t{};
  for(int k=0;k<8;k++) for(int n=0;n<8;n++){
    double s = (k==0) ? 0.35355339059327376220 : 0.5; // sqrt(1/8), sqrt(2/8)
    t.d[k][n] = s * cospi16((2*n+1)*k);
  }
  return t;
}
constexpr DTab DT = make_dtab();

constexpr ull make_fmask(){ // bit u*8+v set iff 3 <= u+v <= 8
  ull m = 0;
  for(int u=0;u<8;u++) for(int v=0;v<8;v++){
    int s=u+v; if(s>=3 && s<=8) m |= (1ULL << (u*8+v));
  }
  return m;
}
constexpr ull FMASK = make_fmask();  // 37 bits set

// ---------------- kernels ----------------

// fused: stego = cover (copy), map = 0, per-block fp64 variance,
// per-WG min/max partials (no atomics), zero bins + candidate counter
__global__ __launch_bounds__(256) void k_stats(const float* __restrict__ cover,
    float* __restrict__ out, double* __restrict__ var,
    unsigned* __restrict__ bins, unsigned* __restrict__ cand_cnt,
    ull* __restrict__ wgmn, ull* __restrict__ wgmx){
  int tid = threadIdx.x;
  int i = blockIdx.x*256 + tid;             // block id over (b,c,n,m)
  if(i < HIST) bins[i] = 0u;
  if(i == HIST) *cand_cnt = 0u;
  int m = i & 63, n = (i>>6)&63, bc = i>>12;
  const float* p  = cover + ((size_t)bc*HW + (size_t)n*8)*HW + (size_t)m*8;
  float*       po = out   + ((size_t)bc*HW + (size_t)n*8)*HW + (size_t)m*8;
  double s1=0.0, s2=0.0;
#pragma unroll
  for(int r=0;r<8;r++){
    const float4* q = (const float4*)(p + (size_t)r*HW);
    float4 a = q[0], b = q[1];
    float4* w = (float4*)(po + (size_t)r*HW);
    w[0]=a; w[1]=b;
    double x;
    x=(double)a.x; s1+=x; s2+=x*x;
    x=(double)a.y; s1+=x; s2+=x*x;
    x=(double)a.z; s1+=x; s2+=x*x;
    x=(double)a.w; s1+=x; s2+=x*x;
    x=(double)b.x; s1+=x; s2+=x*x;
    x=(double)b.y; s1+=x; s2+=x*x;
    x=(double)b.z; s1+=x; s2+=x*x;
    x=(double)b.w; s1+=x; s2+=x*x;
  }
  double mean = s1*(1.0/64.0);
  double v = s2*(1.0/64.0) - mean*mean;
  if(v < 0.0) v = 0.0;
  var[i] = v;
  // zero the embedding map for this block (fixed up later for eligible blocks)
  float4 z = make_float4(0.f,0.f,0.f,0.f);
  float4* pm = (float4*)(out + (size_t)STEGO_N + (size_t)i*64);
#pragma unroll
  for(int j=0;j<16;j++) pm[j] = z;
  // per-WG min/max of variance bits (var>=0 so u64 bit order == value order)
  __shared__ ull smn[256], smx[256];
  ull bits = (ull)__double_as_longlong(v);
  smn[tid]=bits; smx[tid]=bits;
  __syncthreads();
  for(int off=128; off>0; off>>=1){
    if(tid<off){
      if(smn[tid+off] < smn[tid]) smn[tid]=smn[tid+off];
      if(smx[tid+off] > smx[tid]) smx[tid]=smx[tid+off];
    }
    __syncthreads();
  }
  if(tid==0){ wgmn[blockIdx.x]=smn[0]; wgmx[blockIdx.x]=smx[0]; }
}

// redundant, deterministic reduce of the 384 per-WG min/max partials.
// min/max are order-independent -> bitwise identical result in every WG/kernel.
__device__ __forceinline__ void minmax384(const ull* __restrict__ wgmn,
    const ull* __restrict__ wgmx, ull* sred, double& mn, double& mx){
  int tid = threadIdx.x;
  ull a = (tid<NWG384) ? wgmn[tid] : 0xFFFFFFFFFFFFFFFFULL;
  ull b = (tid<NWG384) ? wgmx[tid] : 0ULL;
  sred[tid]=a; sred[1024+tid]=b;
  __syncthreads();
  for(int off=512; off>0; off>>=1){
    if(tid<off){
      if(sred[tid+off] < sred[tid]) sred[tid]=sred[tid+off];
      if(sred[1024+tid+off] > sred[1024+tid]) sred[1024+tid]=sred[1024+tid+off];
    }
    __syncthreads();
  }
  mn = __longlong_as_double((long long)sred[0]);
  mx = __longlong_as_double((long long)sred[1024]);
  __syncthreads();
}

__device__ __forceinline__ int binof(double v, double mn, double scale){
  int b = (int)((v - mn) * scale);          // sub then mul then trunc: no fma, deterministic
  if(b > HIST-1) b = HIST-1;
  if(b < 0) b = 0;
  return b;
}

// 16K-bin histogram of variance over [mn,mx]; LDS hist, sparse global merge
__global__ __launch_bounds__(1024) void k_hist(const double* __restrict__ var,
    const ull* __restrict__ wgmn, const ull* __restrict__ wgmx,
    unsigned* __restrict__ bins){
  __shared__ unsigned h[HIST];              // 64 KB
  __shared__ ull sred[2048];                // 16 KB
  int tid = threadIdx.x;
  double mn, mx;
  minmax384(wgmn, wgmx, sred, mn, mx);
  double scale = (double)HIST / (mx - mn);
  for(int j=tid;j<HIST;j+=1024) h[j]=0u;
  __syncthreads();
  int i = blockIdx.x*1024 + tid;
  atomicAdd(&h[binof(var[i], mn, scale)], 1u);
  __syncthreads();
  for(int j=tid;j<HIST;j+=1024){
    unsigned c=h[j];
    if(c) atomicAdd(&bins[j], c);
  }
}

// every WG redundantly locates the bins holding RANK0/RANK1 (+ below-count),
// then gathers candidate variance bit-patterns from those bins. WG0 publishes desc.
__global__ __launch_bounds__(1024) void k_gather(const double* __restrict__ var,
    const unsigned* __restrict__ bins, const ull* __restrict__ wgmn,
    const ull* __restrict__ wgmx, unsigned* __restrict__ cand_cnt,
    ull* __restrict__ cand, int* __restrict__ desc){
  __shared__ ull sred[2048];
  __shared__ unsigned sb[1024];
  __shared__ int sdesc[3];                  // b0, b1, count-below-b0
  int tid = threadIdx.x;
  double mn, mx;
  minmax384(wgmn, wgmx, sred, mn, mx);
  double scale = (double)HIST / (mx - mn);
  // per-thread sum of its 16 bins, then inclusive scan over 1024 threads
  int base = tid*16;
  unsigned ls = 0;
#pragma unroll
  for(int k=0;k<16;k++) ls += bins[base+k];
  sb[tid]=ls; __syncthreads();
  for(int off=1;off<1024;off<<=1){
    unsigned add = (tid>=off)? sb[tid-off] : 0u;
    __syncthreads();
    sb[tid]+=add;
    __syncthreads();
  }
  unsigned incl = sb[tid], excl = incl - ls;
  if((unsigned)RANK0 >= excl && (unsigned)RANK0 < incl){
    unsigned c = excl;
    for(int k=0;k<16;k++){
      unsigned bc = bins[base+k];
      if((unsigned)RANK0 < c+bc){ sdesc[0]=base+k; sdesc[2]=(int)c; break; }
      c += bc;
    }
  }
  if((unsigned)RANK1 >= excl && (unsigned)RANK1 < incl){
    unsigned c = excl;
    for(int k=0;k<16;k++){
      unsigned bc = bins[base+k];
      if((unsigned)RANK1 < c+bc){ sdesc[1]=base+k; break; }
      c += bc;
    }
  }
  __syncthreads();
  int b0=sdesc[0], b1=sdesc[1];
  if(blockIdx.x==0 && tid==0){ desc[0]=b0; desc[1]=b1; desc[2]=sdesc[2]; }
  int i = blockIdx.x*1024 + tid;
  double v = var[i];
  int b = binof(v, mn, scale);
  if(b >= b0 && b <= b1){
    unsigned idx = atomicAdd(cand_cnt, 1u);
    if(idx < CANDCAP) cand[idx] = (ull)__double_as_longlong(v);
  }
}

// every WG redundantly rank-selects s[RANK0], s[RANK1] from the tiny candidate
// list -> threshold; then texture flags + WG scan -> packed (flag|prefix), bsums
__global__ __launch_bounds__(1024) void k_tex(const double* __restrict__ var,
    const int* __restrict__ desc, const unsigned* __restrict__ cand_cnt,
    const ull* __restrict__ cand, int* __restrict__ packedP,
    int* __restrict__ bsums){
  __shared__ ull sc[CANDCAP];               // 64 KB
  __shared__ int sb[1024];
  __shared__ double sAB[2];
  int tid = threadIdx.x;
  unsigned Ku = *cand_cnt;
  int K = (Ku < (unsigned)CANDCAP) ? (int)Ku : CANDCAP;
  for(int t=tid;t<K;t+=1024) sc[t]=cand[t];
  int Cb = desc[2];
  __syncthreads();
  int r0 = RANK0 - Cb, r1 = RANK1 - Cb;
  for(int t=tid;t<K;t+=1024){
    ull x = sc[t];
    int cl=0, ce=0;
    for(int j=0;j<K;j++){ cl += (sc[j]<x); ce += (sc[j]==x); }
    if(cl<=r0 && r0<cl+ce) sAB[0]=__longlong_as_double((long long)x);
    if(cl<=r1 && r1<cl+ce) sAB[1]=__longlong_as_double((long long)x);
  }
  __syncthreads();
  double A=sAB[0], Bv=sAB[1];
  double thr = A + 0.9*(Bv - A);            // selection: var_norm>thr <=> var>thr_raw
  int i = blockIdx.x*1024 + tid;
  int f = (var[i] > thr) ? 1 : 0;
  sb[tid]=f; __syncthreads();
  for(int off=1;off<1024;off<<=1){
    int add = (tid>=off)? sb[tid-off] : 0;
    __syncthreads();
    sb[tid]+=add;
    __syncthreads();
  }
  int incl = sb[tid];
  packedP[i] = (int)((f ? 0x80000000u : 0u) | (unsigned)(incl - f));
  if(tid==1023) bsums[blockIdx.x]=incl;
}

// WG g: prefix of bsums[0..g) via tree reduce (plain loads), queue eligible
// blocks, wave-shuffle fp64 DCT embed
__global__ __launch_bounds__(1024) void k_embed(const float* __restrict__ cover,
    const int* __restrict__ secret, const int* __restrict__ packedP,
    const int* __restrict__ bsums, float* __restrict__ out){
  __shared__ int sb[1024];
  __shared__ int qi[128], qs[128];
  __shared__ int qcnt;
  int tid = threadIdx.x;
  int g = blockIdx.x;
  int i = g*1024 + tid;
  if(tid==0) qcnt = 0;
  sb[tid] = (tid<g) ? bsums[tid] : 0;
  __syncthreads();
  for(int off=512; off>0; off>>=1){
    if(tid<off) sb[tid] += sb[tid+off];
    __syncthreads();
  }
  int O = sb[0];
  unsigned pp = (unsigned)packedP[i];
  int f = (int)(pp>>31);
  int P = (int)(pp & 0x7FFFFFFFu);
  int S = O + P;                            // # selected blocks strictly before i
  if(f && S < ELIG){
    int q = atomicAdd(&qcnt, 1);
    qi[q]=i; qs[q]=S;
  }
  __syncthreads();
  int nq = qcnt;
  if(nq == 0) return;

  // wave-parallel embed: lane l owns coefficient/pixel (l>>3, l&7); fp64 via shuffles
  int wid = tid >> 6, lane = tid & 63;
  int lr = lane >> 3, lc = lane & 7;
  for(int q = wid; q < nq; q += 16){
    int bi = qi[q], S2 = qs[q];
    int m = bi & 63, n = (bi>>6)&63, bc = bi>>12, b = bi / NPB;
    const float* p  = cover + ((size_t)bc*HW + (size_t)n*8)*HW + (size_t)m*8;
    float*       po = out   + ((size_t)bc*HW + (size_t)n*8)*HW + (size_t)m*8;
    double x = (double)p[(size_t)lr*HW + lc];     // X[lr][lc]
    // stage1: T1[r][v] = sum_j X[r][j]*D[v][j]
    double t1 = 0.0;
#pragma unroll
    for(int j=0;j<8;j++) t1 += __shfl(x, lr*8+j) * DT.d[lc][j];
    // stage2: C[u][v] = sum_k D[u][k]*T1[k][v]
    double coef = 0.0;
#pragma unroll
    for(int k=0;k<8;k++) coef += DT.d[lr][k] * __shfl(t1, k*8+lc);
    // embedding
    bool sel = (FMASK>>lane)&1ULL;
    float mv = 0.f;
    if(sel){
      int fp  = (int)__popcll(FMASK & ((1ULL<<lane)-1ULL));
      int ord = 37*S2 + fp;
      if(ord < NUMBITS){
        mv = 1.f;
        double rnd = rint(coef);                  // round half-to-even == jnp.round
        int lsb = ((int)fabs(rnd)) & 1;
        int bit = secret[(size_t)b*NUMBITS + ord];
        if(lsb != bit) coef += ((coef>=0.0)?1.0:-1.0)*(2.0*(double)bit-1.0)*0.5;
      }
    }
    out[(size_t)STEGO_N + (size_t)bi*64 + lane] = mv;
    // inv stage1: T2[r][v] = sum_u D[u][r]*M[u][v]
    double t2 = 0.0;
#pragma unroll
    for(int u=0;u<8;u++) t2 += DT.d[u][lr] * __shfl(coef, u*8+lc);
    // inv stage2: pix[r][k] = sum_q T2[r][q]*D[q][k]
    double px = 0.0;
#pragma unroll
    for(int qq=0;qq<8;qq++) px += __shfl(t2, lr*8+qq) * DT.d[qq][lc];
    po[(size_t)lr*HW + lc] = (float)px;
  }
}

// ---------------- host launch ----------------
extern "C" void kernel_launch(void* const* d_in, const int* in_sizes, int n_in,
                              void* d_out, int out_size, void* d_ws, size_t ws_size,
                              hipStream_t stream) {
  const float* cover  = (const float*)d_in[0];
  const int*   secret = (const int*)d_in[1];
  float* out = (float*)d_out;
  char*  ws  = (char*)d_ws;

  // ws layout (bytes)
  double*   var      = (double*)(ws);                 // 98304*8  = 786432
  unsigned* bins     = (unsigned*)(ws + 786432);      // 16384*4  -> 852: 786432+65536=851968
  ull*      wgmn     = (ull*)(ws + 851968);           // 384*8    -> 855040
  ull*      wgmx     = (ull*)(ws + 855040);           // 384*8    -> 858112
  int*      desc     = (int*)(ws + 858112);           // 3 ints (pad 32) -> 858144
  unsigned* cand_cnt = (unsigned*)(ws + 858144);      // 4 (pad 8) -> 858152
  ull*      cand     = (ull*)(ws + 858152);           // 8192*8   -> 923688
  int*      packedP  = (int*)(ws + 923688);           // 98304*4  -> 1316904
  int*      bsums    = (int*)(ws + 1316904);          // 96*4     -> 1317288

  k_stats <<<NWG384,    256, 0, stream>>>(cover, out, var, bins, cand_cnt, wgmn, wgmx);
  k_hist  <<<NBLK/1024, 1024, 0, stream>>>(var, wgmn, wgmx, bins);
  k_gather<<<NBLK/1024, 1024, 0, stream>>>(var, bins, wgmn, wgmx, cand_cnt, cand, desc);
  k_tex   <<<NBLK/1024, 1024, 0, stream>>>(var, desc, cand_cnt, cand, packedP, bsums);
  k_embed <<<NBLK/1024, 1024, 0, stream>>>(cover, secret, packedP, bsums, out);
}